// Round 1
// baseline (10078.461 us; speedup 1.0000x reference)
//
#include <hip/hip_runtime.h>
#include <hip/hip_bf16.h>
#include <cmath>
#include <cstddef>

// Problem constants
#define BN   8
#define SN   1024
#define DMN  512
#define HN   8
#define DKN  64
#define DFFN 2048

// ---------------- Global LayerNorm: normalize over (S, DM) per batch ----------------
__global__ __launch_bounds__(1024) void ln_kernel(const float* __restrict__ X,
                                                  float* __restrict__ Y) {
  const int b = blockIdx.x;
  const int t = threadIdx.x;
  const int N = SN * DMN;     // 524288
  const int NV = N / 4;
  const float4* Xv = (const float4*)(X + (size_t)b * N);
  float4* Yv = (float4*)(Y + (size_t)b * N);
  float s = 0.f, s2 = 0.f;
  for (int i = t; i < NV; i += 1024) {
    float4 x = Xv[i];
    s  += x.x + x.y + x.z + x.w;
    s2 += x.x*x.x + x.y*x.y + x.z*x.z + x.w*x.w;
  }
  __shared__ float rs[1024];
  __shared__ float rq[1024];
  rs[t] = s; rq[t] = s2;
  __syncthreads();
  for (int off = 512; off > 0; off >>= 1) {
    if (t < off) { rs[t] += rs[t + off]; rq[t] += rq[t + off]; }
    __syncthreads();
  }
  const float inv_n = 1.f / (float)N;
  const float mu   = rs[0] * inv_n;
  const float var  = rq[0] * inv_n - mu * mu;
  const float rstd = rsqrtf(var + 1e-5f);
  for (int i = t; i < NV; i += 1024) {
    float4 x = Xv[i];
    float4 y;
    y.x = (x.x - mu) * rstd;
    y.y = (x.y - mu) * rstd;
    y.z = (x.z - mu) * rstd;
    y.w = (x.w - mu) * rstd;
    Yv[i] = y;
  }
}

// ---------------- GEMM: C[M,N] = A[M,K] * W[N,K]^T + bias (+ReLU) (+res) ----------------
// 64x64 tile per 256-thread block, 4x4 per thread, K-tile 16.
template<bool RELU, bool RES>
__global__ __launch_bounds__(256) void gemm_bt(const float* __restrict__ A,
                                               const float* __restrict__ W,
                                               const float* __restrict__ bias,
                                               const float* __restrict__ res,
                                               float* __restrict__ C,
                                               int M, int N, int K) {
  __shared__ float As[16][64];
  __shared__ float Ws[16][64];
  const int n0 = blockIdx.x * 64;
  const int m0 = blockIdx.y * 64;
  const int t  = threadIdx.x;
  const int tx = t & 15;        // 0..15 -> 4 output cols
  const int ty = t >> 4;        // 0..15 -> 4 output rows
  const int lr = t >> 2;        // 0..63 load row
  const int lc = (t & 3) * 4;   // 0,4,8,12 load k-offset
  float acc[4][4] = {};
  for (int k0 = 0; k0 < K; k0 += 16) {
    float4 a4 = *(const float4*)(A + (size_t)(m0 + lr) * K + k0 + lc);
    float4 w4 = *(const float4*)(W + (size_t)(n0 + lr) * K + k0 + lc);
    As[lc + 0][lr] = a4.x; As[lc + 1][lr] = a4.y; As[lc + 2][lr] = a4.z; As[lc + 3][lr] = a4.w;
    Ws[lc + 0][lr] = w4.x; Ws[lc + 1][lr] = w4.y; Ws[lc + 2][lr] = w4.z; Ws[lc + 3][lr] = w4.w;
    __syncthreads();
#pragma unroll
    for (int kk = 0; kk < 16; ++kk) {
      float a[4], bb[4];
#pragma unroll
      for (int i = 0; i < 4; ++i) a[i] = As[kk][ty * 4 + i];
#pragma unroll
      for (int j = 0; j < 4; ++j) bb[j] = Ws[kk][tx * 4 + j];
#pragma unroll
      for (int i = 0; i < 4; ++i)
#pragma unroll
        for (int j = 0; j < 4; ++j)
          acc[i][j] += a[i] * bb[j];
    }
    __syncthreads();
  }
#pragma unroll
  for (int i = 0; i < 4; ++i) {
    const int m = m0 + ty * 4 + i;
    const int n = n0 + tx * 4;
    float4 o;
    float* op = (float*)&o;
#pragma unroll
    for (int j = 0; j < 4; ++j) {
      float v = acc[i][j] + bias[n + j];
      if (RELU) v = fmaxf(v, 0.f);
      if (RES)  v += res[(size_t)m * N + n + j];
      op[j] = v;
    }
    *(float4*)(C + (size_t)m * N + n) = o;
  }
}

// ---------------- Attention: one block per (q-row, h, b) ----------------
// Q,K,V stored as [B, S, H, 64]; O written as [B, S, H, 64] (== concat layout [B,S,H*DV]).
__global__ __launch_bounds__(256) void attn_kernel(const float* __restrict__ Q,
                                                   const float* __restrict__ K,
                                                   const float* __restrict__ V,
                                                   float* __restrict__ O,
                                                   int causal) {
  const int r = blockIdx.x, h = blockIdx.y, b = blockIdx.z;
  const int t = threadIdx.x;
  __shared__ float qs[DKN];
  __shared__ float sc[SN];
  __shared__ float red[256];
  __shared__ float po[4][DKN];
  const size_t qoff = (((size_t)b * SN + r) * HN + h) * DKN;
  if (t < DKN) qs[t] = Q[qoff + t];
  __syncthreads();

  float lmax = -INFINITY;
  for (int s = t; s < SN; s += 256) {
    const float* kp = K + (((size_t)b * SN + s) * HN + h) * DKN;
    float d = 0.f;
#pragma unroll
    for (int k = 0; k < DKN; ++k) d += qs[k] * kp[k];
    d *= 0.125f;  // 1/sqrt(64)
    if (causal && s > r) d = -INFINITY;
    sc[s] = d;
    lmax = fmaxf(lmax, d);
  }
  red[t] = lmax;
  __syncthreads();
  for (int off = 128; off > 0; off >>= 1) {
    if (t < off) red[t] = fmaxf(red[t], red[t + off]);
    __syncthreads();
  }
  const float mx = red[0];
  __syncthreads();

  float lsum = 0.f;
  for (int s = t; s < SN; s += 256) {
    float e = __expf(sc[s] - mx);
    sc[s] = e;
    lsum += e;
  }
  red[t] = lsum;
  __syncthreads();
  for (int off = 128; off > 0; off >>= 1) {
    if (t < off) red[t] += red[t + off];
    __syncthreads();
  }
  const float inv = 1.f / red[0];

  const int g = t >> 6, v = t & 63;
  float acc = 0.f;
  for (int s = g; s < SN; s += 4) {
    acc += sc[s] * V[(((size_t)b * SN + s) * HN + h) * DKN + v];
  }
  po[g][v] = acc;
  __syncthreads();
  if (t < DKN) {
    float o = (po[0][t] + po[1][t] + po[2][t] + po[3][t]) * inv;
    O[(((size_t)b * SN + r) * HN + h) * DKN + t] = o;
  }
}

extern "C" void kernel_launch(void* const* d_in, const int* in_sizes, int n_in,
                              void* d_out, int out_size, void* d_ws, size_t ws_size,
                              hipStream_t stream) {
  const float* x_enc = (const float*)d_in[0];
  const float* x_dec = (const float*)d_in[1];
  const float* mq_w = (const float*)d_in[2];  const float* mq_b = (const float*)d_in[3];
  const float* mk_w = (const float*)d_in[4];  const float* mk_b = (const float*)d_in[5];
  const float* mv_w = (const float*)d_in[6];  const float* mv_b = (const float*)d_in[7];
  const float* mo_w = (const float*)d_in[8];  const float* mo_b = (const float*)d_in[9];
  const float* cq_w = (const float*)d_in[10]; const float* cq_b = (const float*)d_in[11];
  const float* ck_w = (const float*)d_in[12]; const float* ck_b = (const float*)d_in[13];
  const float* cv_w = (const float*)d_in[14]; const float* cv_b = (const float*)d_in[15];
  const float* co_w = (const float*)d_in[16]; const float* co_b = (const float*)d_in[17];
  const float* f1_w = (const float*)d_in[18]; const float* f1_b = (const float*)d_in[19];
  const float* f2_w = (const float*)d_in[20]; const float* f2_b = (const float*)d_in[21];
  float* out = (float*)d_out;

  const size_t SLOT = (size_t)BN * SN * DMN;  // 4194304 floats
  float* w  = (float*)d_ws;
  float* o0 = w + 0 * SLOT;   // norm buffer (xdn / cur_n / res_n) and cross-attn concat
  float* o1 = w + 1 * SLOT;   // q / enc_n ; ff1 spans o1..o4 in FF phase
  float* o2 = w + 2 * SLOT;   // k / qc
  float* o3 = w + 3 * SLOT;   // v / kc
  float* o4 = w + 4 * SLOT;   // concat / vc
  float* o5 = w + 5 * SLOT;   // current
  float* o6 = w + 6 * SLOT;   // result
  float* ff1 = o1;            // [8192, 2048] in FF phase

  const int M = BN * SN;  // 8192
  dim3 g512(512 / 64, M / 64);
  dim3 g2048(2048 / 64, M / 64);
  dim3 attn_grid(SN, HN, BN);

  // ---- masked self-attention block ----
  ln_kernel<<<BN, 1024, 0, stream>>>(x_dec, o0);
  gemm_bt<false, false><<<g512, 256, 0, stream>>>(o0, mq_w, mq_b, nullptr, o1, M, 512, 512);
  gemm_bt<false, false><<<g512, 256, 0, stream>>>(o0, mk_w, mk_b, nullptr, o2, M, 512, 512);
  gemm_bt<false, false><<<g512, 256, 0, stream>>>(o0, mv_w, mv_b, nullptr, o3, M, 512, 512);
  attn_kernel<<<attn_grid, 256, 0, stream>>>(o1, o2, o3, o4, 1);
  gemm_bt<false, true><<<g512, 256, 0, stream>>>(o4, mo_w, mo_b, x_dec, o5, M, 512, 512);

  // ---- cross-attention block ----
  ln_kernel<<<BN, 1024, 0, stream>>>(o5, o0);     // cur_n
  ln_kernel<<<BN, 1024, 0, stream>>>(x_enc, o1);  // enc_n
  gemm_bt<false, false><<<g512, 256, 0, stream>>>(o0, cq_w, cq_b, nullptr, o2, M, 512, 512);
  gemm_bt<false, false><<<g512, 256, 0, stream>>>(o1, ck_w, ck_b, nullptr, o3, M, 512, 512);
  gemm_bt<false, false><<<g512, 256, 0, stream>>>(o1, cv_w, cv_b, nullptr, o4, M, 512, 512);
  attn_kernel<<<attn_grid, 256, 0, stream>>>(o2, o3, o4, o0, 0);
  gemm_bt<false, true><<<g512, 256, 0, stream>>>(o0, co_w, co_b, o5, o6, M, 512, 512);

  // ---- feedforward block ----
  ln_kernel<<<BN, 1024, 0, stream>>>(o6, o0);     // res_n
  gemm_bt<true, false><<<g2048, 256, 0, stream>>>(o0, f1_w, f1_b, nullptr, ff1, M, 2048, 512);
  gemm_bt<false, true><<<g512, 256, 0, stream>>>(ff1, f2_w, f2_b, o6, out, M, 512, 2048);
}

// Round 2
// 2058.995 us; speedup vs baseline: 4.8948x; 4.8948x over previous
//
#include <hip/hip_runtime.h>
#include <hip/hip_bf16.h>
#include <cmath>
#include <cstddef>

// Problem constants
#define BN   8
#define SN   1024
#define DMN  512
#define HN   8
#define DKN  64
#define DFFN 2048

// ---------------- Global LayerNorm: normalize over (S, DM) per batch ----------------
__global__ __launch_bounds__(1024) void ln_kernel(const float* __restrict__ X,
                                                  float* __restrict__ Y) {
  const int b = blockIdx.x;
  const int t = threadIdx.x;
  const int N = SN * DMN;     // 524288
  const int NV = N / 4;
  const float4* Xv = (const float4*)(X + (size_t)b * N);
  float4* Yv = (float4*)(Y + (size_t)b * N);
  float s = 0.f, s2 = 0.f;
  for (int i = t; i < NV; i += 1024) {
    float4 x = Xv[i];
    s  += x.x + x.y + x.z + x.w;
    s2 += x.x*x.x + x.y*x.y + x.z*x.z + x.w*x.w;
  }
  __shared__ float rs[1024];
  __shared__ float rq[1024];
  rs[t] = s; rq[t] = s2;
  __syncthreads();
  for (int off = 512; off > 0; off >>= 1) {
    if (t < off) { rs[t] += rs[t + off]; rq[t] += rq[t + off]; }
    __syncthreads();
  }
  const float inv_n = 1.f / (float)N;
  const float mu   = rs[0] * inv_n;
  const float var  = rq[0] * inv_n - mu * mu;
  const float rstd = rsqrtf(var + 1e-5f);
  for (int i = t; i < NV; i += 1024) {
    float4 x = Xv[i];
    float4 y;
    y.x = (x.x - mu) * rstd;
    y.y = (x.y - mu) * rstd;
    y.z = (x.z - mu) * rstd;
    y.w = (x.w - mu) * rstd;
    Yv[i] = y;
  }
}

// ---------------- GEMM: C[M,N] = A[M,K] * W[N,K]^T + bias (+ReLU) (+res) ----------------
// 64x64 tile per 256-thread block, 4x4 per thread, K-tile 16.
template<bool RELU, bool RES>
__global__ __launch_bounds__(256) void gemm_bt(const float* __restrict__ A,
                                               const float* __restrict__ W,
                                               const float* __restrict__ bias,
                                               const float* __restrict__ res,
                                               float* __restrict__ C,
                                               int M, int N, int K) {
  __shared__ float As[16][64];
  __shared__ float Ws[16][64];
  const int n0 = blockIdx.x * 64;
  const int m0 = blockIdx.y * 64;
  const int t  = threadIdx.x;
  const int tx = t & 15;        // 0..15 -> 4 output cols
  const int ty = t >> 4;        // 0..15 -> 4 output rows
  const int lr = t >> 2;        // 0..63 load row
  const int lc = (t & 3) * 4;   // 0,4,8,12 load k-offset
  float acc[4][4] = {};
  for (int k0 = 0; k0 < K; k0 += 16) {
    float4 a4 = *(const float4*)(A + (size_t)(m0 + lr) * K + k0 + lc);
    float4 w4 = *(const float4*)(W + (size_t)(n0 + lr) * K + k0 + lc);
    As[lc + 0][lr] = a4.x; As[lc + 1][lr] = a4.y; As[lc + 2][lr] = a4.z; As[lc + 3][lr] = a4.w;
    Ws[lc + 0][lr] = w4.x; Ws[lc + 1][lr] = w4.y; Ws[lc + 2][lr] = w4.z; Ws[lc + 3][lr] = w4.w;
    __syncthreads();
#pragma unroll
    for (int kk = 0; kk < 16; ++kk) {
      float a[4], bb[4];
#pragma unroll
      for (int i = 0; i < 4; ++i) a[i] = As[kk][ty * 4 + i];
#pragma unroll
      for (int j = 0; j < 4; ++j) bb[j] = Ws[kk][tx * 4 + j];
#pragma unroll
      for (int i = 0; i < 4; ++i)
#pragma unroll
        for (int j = 0; j < 4; ++j)
          acc[i][j] += a[i] * bb[j];
    }
    __syncthreads();
  }
#pragma unroll
  for (int i = 0; i < 4; ++i) {
    const int m = m0 + ty * 4 + i;
    const int n = n0 + tx * 4;
    float4 o;
    float* op = (float*)&o;
#pragma unroll
    for (int j = 0; j < 4; ++j) {
      float v = acc[i][j] + bias[n + j];
      if (RELU) v = fmaxf(v, 0.f);
      if (RES)  v += res[(size_t)m * N + n + j];
      op[j] = v;
    }
    *(float4*)(C + (size_t)m * N + n) = o;
  }
}

// ---------------- Flash-style tiled attention ----------------
// Q,K,V,O as [B, S, H, 64]. One block per (q-tile of 64 rows, h, b).
// 256 threads; thread (ty,tx) owns 4x4 of the 64x64 score/output tile.
// Online softmax: per-row m,l in registers, reduced across the 16-thread
// row group via __shfl_xor (lanes contiguous within wave).
template<int CAUSAL>
__global__ __launch_bounds__(256) void attn_tile(const float* __restrict__ Q,
                                                 const float* __restrict__ K,
                                                 const float* __restrict__ V,
                                                 float* __restrict__ O) {
  const int qt = blockIdx.x;              // 0..15
  const int h  = blockIdx.y, b = blockIdx.z;
  const int t  = threadIdx.x;
  const int tx = t & 15;                  // 4 cols
  const int ty = t >> 4;                  // 4 rows

  __shared__ float Qs[64][65];
  __shared__ float KPs[64][65];           // K tile, reused as P tile
  __shared__ float Vs[64][65];

  const int lr = t >> 2;                  // load row 0..63
  const int lc = (t & 3) * 16;            // load col 0,16,32,48
  const int rowstride = HN * DKN;         // 512 floats

  // load Q tile
  {
    const float* qp = Q + (((size_t)b * SN + qt * 64 + lr) * HN + h) * DKN + lc;
#pragma unroll
    for (int u = 0; u < 4; ++u) {
      float4 x = *(const float4*)(qp + u * 4);
      Qs[lr][lc + u*4 + 0] = x.x; Qs[lr][lc + u*4 + 1] = x.y;
      Qs[lr][lc + u*4 + 2] = x.z; Qs[lr][lc + u*4 + 3] = x.w;
    }
  }

  float m[4], l[4], o[4][4];
#pragma unroll
  for (int i = 0; i < 4; ++i) {
    m[i] = -INFINITY; l[i] = 0.f;
#pragma unroll
    for (int j = 0; j < 4; ++j) o[i][j] = 0.f;
  }

  const int nkt = CAUSAL ? (qt + 1) : (SN / 64);
  for (int kt = 0; kt < nkt; ++kt) {
    __syncthreads();   // prev iter's PV done reading KPs/Vs
    // load K,V tiles
    {
      const float* kp = K + (((size_t)b * SN + kt * 64 + lr) * HN + h) * DKN + lc;
      const float* vp = V + (((size_t)b * SN + kt * 64 + lr) * HN + h) * DKN + lc;
#pragma unroll
      for (int u = 0; u < 4; ++u) {
        float4 x = *(const float4*)(kp + u * 4);
        KPs[lr][lc + u*4 + 0] = x.x; KPs[lr][lc + u*4 + 1] = x.y;
        KPs[lr][lc + u*4 + 2] = x.z; KPs[lr][lc + u*4 + 3] = x.w;
        float4 y = *(const float4*)(vp + u * 4);
        Vs[lr][lc + u*4 + 0] = y.x; Vs[lr][lc + u*4 + 1] = y.y;
        Vs[lr][lc + u*4 + 2] = y.z; Vs[lr][lc + u*4 + 3] = y.w;
      }
    }
    __syncthreads();

    // score tile s = (Q . K^T) * 1/8
    float s[4][4] = {};
#pragma unroll 8
    for (int k = 0; k < 64; ++k) {
      float a[4], bb[4];
#pragma unroll
      for (int i = 0; i < 4; ++i) a[i] = Qs[ty * 4 + i][k];
#pragma unroll
      for (int j = 0; j < 4; ++j) bb[j] = KPs[tx * 4 + j][k];
#pragma unroll
      for (int i = 0; i < 4; ++i)
#pragma unroll
        for (int j = 0; j < 4; ++j)
          s[i][j] += a[i] * bb[j];
    }
#pragma unroll
    for (int i = 0; i < 4; ++i)
#pragma unroll
      for (int j = 0; j < 4; ++j)
        s[i][j] *= 0.125f;

    if (CAUSAL && kt == qt) {
#pragma unroll
      for (int i = 0; i < 4; ++i)
#pragma unroll
        for (int j = 0; j < 4; ++j)
          if (tx * 4 + j > ty * 4 + i) s[i][j] = -INFINITY;
    }

    // online softmax update
    float p[4][4], rsum[4];
#pragma unroll
    for (int i = 0; i < 4; ++i) {
      float rm = fmaxf(fmaxf(s[i][0], s[i][1]), fmaxf(s[i][2], s[i][3]));
#pragma unroll
      for (int msk = 1; msk < 16; msk <<= 1)
        rm = fmaxf(rm, __shfl_xor(rm, msk));
      const float mn = fmaxf(m[i], rm);
      const float sc = __expf(m[i] - mn);
      l[i] *= sc;
#pragma unroll
      for (int j = 0; j < 4; ++j) o[i][j] *= sc;
      float ps = 0.f;
#pragma unroll
      for (int j = 0; j < 4; ++j) { p[i][j] = __expf(s[i][j] - mn); ps += p[i][j]; }
#pragma unroll
      for (int msk = 1; msk < 16; msk <<= 1)
        ps += __shfl_xor(ps, msk);
      l[i] += ps;
      m[i] = mn;
    }

    __syncthreads();   // all threads done reading KPs (K)
    // write P tile into KPs
#pragma unroll
    for (int i = 0; i < 4; ++i)
#pragma unroll
      for (int j = 0; j < 4; ++j)
        KPs[ty * 4 + i][tx * 4 + j] = p[i][j];
    __syncthreads();

    // O += P . V
#pragma unroll 8
    for (int sx = 0; sx < 64; ++sx) {
      float pa[4], vb[4];
#pragma unroll
      for (int i = 0; i < 4; ++i) pa[i] = KPs[ty * 4 + i][sx];
#pragma unroll
      for (int j = 0; j < 4; ++j) vb[j] = Vs[sx][tx * 4 + j];
#pragma unroll
      for (int i = 0; i < 4; ++i)
#pragma unroll
        for (int j = 0; j < 4; ++j)
          o[i][j] += pa[i] * vb[j];
    }
  }

  // final normalize + store
#pragma unroll
  for (int i = 0; i < 4; ++i) {
    const float inv = 1.f / l[i];
    float4 ov;
    ov.x = o[i][0] * inv; ov.y = o[i][1] * inv;
    ov.z = o[i][2] * inv; ov.w = o[i][3] * inv;
    float* op = O + (((size_t)b * SN + qt * 64 + ty * 4 + i) * HN + h) * DKN + tx * 4;
    *(float4*)op = ov;
  }
}

extern "C" void kernel_launch(void* const* d_in, const int* in_sizes, int n_in,
                              void* d_out, int out_size, void* d_ws, size_t ws_size,
                              hipStream_t stream) {
  const float* x_enc = (const float*)d_in[0];
  const float* x_dec = (const float*)d_in[1];
  const float* mq_w = (const float*)d_in[2];  const float* mq_b = (const float*)d_in[3];
  const float* mk_w = (const float*)d_in[4];  const float* mk_b = (const float*)d_in[5];
  const float* mv_w = (const float*)d_in[6];  const float* mv_b = (const float*)d_in[7];
  const float* mo_w = (const float*)d_in[8];  const float* mo_b = (const float*)d_in[9];
  const float* cq_w = (const float*)d_in[10]; const float* cq_b = (const float*)d_in[11];
  const float* ck_w = (const float*)d_in[12]; const float* ck_b = (const float*)d_in[13];
  const float* cv_w = (const float*)d_in[14]; const float* cv_b = (const float*)d_in[15];
  const float* co_w = (const float*)d_in[16]; const float* co_b = (const float*)d_in[17];
  const float* f1_w = (const float*)d_in[18]; const float* f1_b = (const float*)d_in[19];
  const float* f2_w = (const float*)d_in[20]; const float* f2_b = (const float*)d_in[21];
  float* out = (float*)d_out;

  const size_t SLOT = (size_t)BN * SN * DMN;  // 4194304 floats
  float* w  = (float*)d_ws;
  float* o0 = w + 0 * SLOT;
  float* o1 = w + 1 * SLOT;
  float* o2 = w + 2 * SLOT;
  float* o3 = w + 3 * SLOT;
  float* o4 = w + 4 * SLOT;
  float* o5 = w + 5 * SLOT;
  float* o6 = w + 6 * SLOT;
  float* ff1 = o1;            // [8192, 2048] in FF phase

  const int M = BN * SN;  // 8192
  dim3 g512(512 / 64, M / 64);
  dim3 g2048(2048 / 64, M / 64);
  dim3 attn_grid(SN / 64, HN, BN);

  // ---- masked self-attention block ----
  ln_kernel<<<BN, 1024, 0, stream>>>(x_dec, o0);
  gemm_bt<false, false><<<g512, 256, 0, stream>>>(o0, mq_w, mq_b, nullptr, o1, M, 512, 512);
  gemm_bt<false, false><<<g512, 256, 0, stream>>>(o0, mk_w, mk_b, nullptr, o2, M, 512, 512);
  gemm_bt<false, false><<<g512, 256, 0, stream>>>(o0, mv_w, mv_b, nullptr, o3, M, 512, 512);
  attn_tile<1><<<attn_grid, 256, 0, stream>>>(o1, o2, o3, o4);
  gemm_bt<false, true><<<g512, 256, 0, stream>>>(o4, mo_w, mo_b, x_dec, o5, M, 512, 512);

  // ---- cross-attention block ----
  ln_kernel<<<BN, 1024, 0, stream>>>(o5, o0);     // cur_n
  ln_kernel<<<BN, 1024, 0, stream>>>(x_enc, o1);  // enc_n
  gemm_bt<false, false><<<g512, 256, 0, stream>>>(o0, cq_w, cq_b, nullptr, o2, M, 512, 512);
  gemm_bt<false, false><<<g512, 256, 0, stream>>>(o1, ck_w, ck_b, nullptr, o3, M, 512, 512);
  gemm_bt<false, false><<<g512, 256, 0, stream>>>(o1, cv_w, cv_b, nullptr, o4, M, 512, 512);
  attn_tile<0><<<attn_grid, 256, 0, stream>>>(o2, o3, o4, o0);
  gemm_bt<false, true><<<g512, 256, 0, stream>>>(o0, co_w, co_b, o5, o6, M, 512, 512);

  // ---- feedforward block ----
  ln_kernel<<<BN, 1024, 0, stream>>>(o6, o0);     // res_n
  gemm_bt<true, false><<<g2048, 256, 0, stream>>>(o0, f1_w, f1_b, nullptr, ff1, M, 2048, 512);
  gemm_bt<false, true><<<g512, 256, 0, stream>>>(ff1, f2_w, f2_b, o6, out, M, 512, 2048);
}

// Round 3
// 976.241 us; speedup vs baseline: 10.3237x; 2.1091x over previous
//
#include <hip/hip_runtime.h>
#include <cmath>
#include <cstddef>
#include <cstdint>

// Problem constants
#define BN   8
#define SN   1024
#define DMN  512
#define HN   8
#define DKN  64
#define DFFN 2048

typedef short           bf16x8   __attribute__((ext_vector_type(8)));
typedef float           f32x4    __attribute__((ext_vector_type(4)));
typedef unsigned short  ushortx4 __attribute__((ext_vector_type(4)));
typedef unsigned short  ushortx8 __attribute__((ext_vector_type(8)));
typedef unsigned short  u16;

__device__ __forceinline__ float bf2f(u16 u) {
  return __uint_as_float(((unsigned int)u) << 16);
}
__device__ __forceinline__ u16 f2bf(float f) {
  unsigned int u = __float_as_uint(f);
  u += 0x7FFFu + ((u >> 16) & 1u);          // RNE
  return (u16)(u >> 16);
}
__device__ __forceinline__ void gload_lds16(const u16* gsrc, u16* ldst) {
  __builtin_amdgcn_global_load_lds(
      (const __attribute__((address_space(1))) unsigned int*)gsrc,
      (__attribute__((address_space(3))) unsigned int*)ldst,
      16, 0, 0);
}

// ---------------- weight fp32 -> bf16 conversion (all 10 matrices, one kernel) ----------------
// dst layout: mq|mk|mv|mo|cq|ck|cv|co (8 x 262144) then f1 (1048576) then f2 (1048576)
__global__ __launch_bounds__(256) void cvt_weights(
    const float* p0, const float* p1, const float* p2, const float* p3,
    const float* p4, const float* p5, const float* p6, const float* p7,
    const float* p8, const float* p9, u16* __restrict__ dst) {
  const int gi = blockIdx.x * 256 + threadIdx.x;   // group of 4 elems
  const int idx = gi * 4;
  const float* src; int off;
  if (idx < 2097152) {
    const int t = idx >> 18; off = idx & 262143;
    switch (t) {
      case 0: src = p0; break; case 1: src = p1; break;
      case 2: src = p2; break; case 3: src = p3; break;
      case 4: src = p4; break; case 5: src = p5; break;
      case 6: src = p6; break; default: src = p7; break;
    }
  } else if (idx < 3145728) { src = p8; off = idx - 2097152; }
  else                      { src = p9; off = idx - 3145728; }
  float4 v = *(const float4*)(src + off);
  ushortx4 o;
  o[0] = f2bf(v.x); o[1] = f2bf(v.y); o[2] = f2bf(v.z); o[3] = f2bf(v.w);
  *(ushortx4*)(dst + idx) = o;
}

// ---------------- Global LayerNorm (two-pass, 64 blocks per batch), bf16 out ----------------
__global__ __launch_bounds__(256) void ln_sum(const float* __restrict__ X,
                                              float2* __restrict__ part) {
  const int g = blockIdx.x, b = blockIdx.y, t = threadIdx.x;
  const float4* Xv = (const float4*)(X + (size_t)b * (SN * DMN) + (size_t)g * 8192);
  float s = 0.f, s2 = 0.f;
#pragma unroll
  for (int it = 0; it < 8; ++it) {
    float4 x = Xv[t + it * 256];
    s  += x.x + x.y + x.z + x.w;
    s2 += x.x*x.x + x.y*x.y + x.z*x.z + x.w*x.w;
  }
  __shared__ float rs[256], rq[256];
  rs[t] = s; rq[t] = s2;
  __syncthreads();
  for (int off = 128; off > 0; off >>= 1) {
    if (t < off) { rs[t] += rs[t + off]; rq[t] += rq[t + off]; }
    __syncthreads();
  }
  if (t == 0) part[b * 64 + g] = make_float2(rs[0], rq[0]);
}

__global__ __launch_bounds__(256) void ln_norm(const float* __restrict__ X,
                                               const float2* __restrict__ part,
                                               u16* __restrict__ Y) {
  const int g = blockIdx.x, b = blockIdx.y, t = threadIdx.x;
  __shared__ float ss[64], sq[64];
  if (t < 64) { float2 p = part[b * 64 + t]; ss[t] = p.x; sq[t] = p.y; }
  __syncthreads();
  float s = 0.f, q = 0.f;
#pragma unroll
  for (int j = 0; j < 64; ++j) { s += ss[j]; q += sq[j]; }
  const float inv_n = 1.f / (float)(SN * DMN);
  const float mu = s * inv_n;
  const float var = q * inv_n - mu * mu;
  const float rstd = rsqrtf(var + 1e-5f);
  const size_t base = (size_t)b * (SN * DMN) + (size_t)g * 8192;
  const float4* Xv = (const float4*)(X + base);
#pragma unroll
  for (int it = 0; it < 8; ++it) {
    float4 x = Xv[t + it * 256];
    ushortx4 o;
    o[0] = f2bf((x.x - mu) * rstd); o[1] = f2bf((x.y - mu) * rstd);
    o[2] = f2bf((x.z - mu) * rstd); o[3] = f2bf((x.w - mu) * rstd);
    *(ushortx4*)(Y + base + (size_t)(t + it * 256) * 4) = o;
  }
}

// ---------------- bf16 MFMA GEMM: C[M,N] = A[M,K] * W[N,K]^T + bias (+ReLU)(+res fp32) ----------------
// 128x128 tile, BK=32, 256 threads = 4 waves (2x2), each wave 64x64 via 4x4 mfma_16x16x32 frags.
template<bool RELU, bool RES, bool OUT_BF16>
__global__ __launch_bounds__(256) void gemm_mfma(const u16* __restrict__ A,
                                                 const u16* __restrict__ W,
                                                 const float* __restrict__ bias,
                                                 const float* __restrict__ res,
                                                 void* __restrict__ Cv,
                                                 int M, int N, int K) {
  __shared__ u16 As[128 * 32];
  __shared__ u16 Bs[128 * 32];
  const int t = threadIdx.x;
  const int lane = t & 63, w = t >> 6;
  const int wm = w >> 1, wn = w & 1;
  const int m0 = blockIdx.y * 128, n0 = blockIdx.x * 128;

  f32x4 acc[4][4];
#pragma unroll
  for (int i = 0; i < 4; ++i)
#pragma unroll
    for (int j = 0; j < 4; ++j)
      acc[i][j] = (f32x4){0.f, 0.f, 0.f, 0.f};

  const int lrow = lane >> 2;          // 0..15 within 16-row chunk
  const int lcol = (lane & 3) * 8;     // bf16-elem offset within 32-col row
  const int rofs = (lane & 15) * 32 + (lane >> 4) * 8;  // fragment read offset

  for (int k0 = 0; k0 < K; k0 += 32) {
#pragma unroll
    for (int c = 0; c < 2; ++c) {
      const int r0 = w * 32 + c * 16;
      gload_lds16(A + (size_t)(m0 + r0 + lrow) * K + k0 + lcol, &As[r0 * 32]);
      gload_lds16(W + (size_t)(n0 + r0 + lrow) * K + k0 + lcol, &Bs[r0 * 32]);
    }
    __syncthreads();
    bf16x8 af[4], bfr[4];
#pragma unroll
    for (int f = 0; f < 4; ++f) {
      af[f]  = *(const bf16x8*)&As[(wm * 64 + f * 16) * 32 + rofs];
      bfr[f] = *(const bf16x8*)&Bs[(wn * 64 + f * 16) * 32 + rofs];
    }
#pragma unroll
    for (int i = 0; i < 4; ++i)
#pragma unroll
      for (int j = 0; j < 4; ++j)
        acc[i][j] = __builtin_amdgcn_mfma_f32_16x16x32_bf16(af[i], bfr[j], acc[i][j], 0, 0, 0);
    __syncthreads();
  }

  // epilogue: C/D layout col=lane&15, row=(lane>>4)*4+reg  [m89-verified]
  const int crow0 = (lane >> 4) * 4;
  const int ccol  = lane & 15;
  float bv[4];
#pragma unroll
  for (int j = 0; j < 4; ++j) bv[j] = bias[n0 + wn * 64 + j * 16 + ccol];
#pragma unroll
  for (int i = 0; i < 4; ++i) {
#pragma unroll
    for (int r = 0; r < 4; ++r) {
      const int m = m0 + wm * 64 + i * 16 + crow0 + r;
#pragma unroll
      for (int j = 0; j < 4; ++j) {
        const int n = n0 + wn * 64 + j * 16 + ccol;
        float v = acc[i][j][r] + bv[j];
        if (RELU) v = fmaxf(v, 0.f);
        if (RES)  v += res[(size_t)m * N + n];
        if (OUT_BF16) ((u16*)Cv)[(size_t)m * N + n] = f2bf(v);
        else          ((float*)Cv)[(size_t)m * N + n] = v;
      }
    }
  }
}

// ---------------- Flash-style tiled attention (bf16 in/out, fp32 math) ----------------
template<int CAUSAL>
__global__ __launch_bounds__(256) void attn_tile(const u16* __restrict__ Q,
                                                 const u16* __restrict__ K,
                                                 const u16* __restrict__ V,
                                                 u16* __restrict__ O) {
  const int qt = blockIdx.x;
  const int h  = blockIdx.y, b = blockIdx.z;
  const int t  = threadIdx.x;
  const int tx = t & 15;
  const int ty = t >> 4;

  __shared__ float Qs[64][65];
  __shared__ float KPs[64][65];
  __shared__ float Vs[64][65];

  const int lr = t >> 2;
  const int lc = (t & 3) * 16;

  // load Q tile (bf16 -> fp32)
  {
    const u16* qp = Q + (((size_t)b * SN + qt * 64 + lr) * HN + h) * DKN + lc;
    ushortx8 u0 = *(const ushortx8*)qp;
    ushortx8 u1 = *(const ushortx8*)(qp + 8);
#pragma unroll
    for (int e = 0; e < 8; ++e) {
      Qs[lr][lc + e]     = bf2f(u0[e]);
      Qs[lr][lc + 8 + e] = bf2f(u1[e]);
    }
  }

  float m[4], l[4], o[4][4];
#pragma unroll
  for (int i = 0; i < 4; ++i) {
    m[i] = -INFINITY; l[i] = 0.f;
#pragma unroll
    for (int j = 0; j < 4; ++j) o[i][j] = 0.f;
  }

  const int nkt = CAUSAL ? (qt + 1) : (SN / 64);
  for (int kt = 0; kt < nkt; ++kt) {
    __syncthreads();
    {
      const u16* kp = K + (((size_t)b * SN + kt * 64 + lr) * HN + h) * DKN + lc;
      const u16* vp = V + (((size_t)b * SN + kt * 64 + lr) * HN + h) * DKN + lc;
      ushortx8 k0 = *(const ushortx8*)kp;
      ushortx8 k1 = *(const ushortx8*)(kp + 8);
      ushortx8 v0 = *(const ushortx8*)vp;
      ushortx8 v1 = *(const ushortx8*)(vp + 8);
#pragma unroll
      for (int e = 0; e < 8; ++e) {
        KPs[lr][lc + e]     = bf2f(k0[e]);
        KPs[lr][lc + 8 + e] = bf2f(k1[e]);
        Vs[lr][lc + e]      = bf2f(v0[e]);
        Vs[lr][lc + 8 + e]  = bf2f(v1[e]);
      }
    }
    __syncthreads();

    float s[4][4] = {};
#pragma unroll 8
    for (int k = 0; k < 64; ++k) {
      float a[4], bb[4];
#pragma unroll
      for (int i = 0; i < 4; ++i) a[i] = Qs[ty * 4 + i][k];
#pragma unroll
      for (int j = 0; j < 4; ++j) bb[j] = KPs[tx * 4 + j][k];
#pragma unroll
      for (int i = 0; i < 4; ++i)
#pragma unroll
        for (int j = 0; j < 4; ++j)
          s[i][j] += a[i] * bb[j];
    }
#pragma unroll
    for (int i = 0; i < 4; ++i)
#pragma unroll
      for (int j = 0; j < 4; ++j)
        s[i][j] *= 0.125f;

    if (CAUSAL && kt == qt) {
#pragma unroll
      for (int i = 0; i < 4; ++i)
#pragma unroll
        for (int j = 0; j < 4; ++j)
          if (tx * 4 + j > ty * 4 + i) s[i][j] = -INFINITY;
    }

    float p[4][4];
#pragma unroll
    for (int i = 0; i < 4; ++i) {
      float rm = fmaxf(fmaxf(s[i][0], s[i][1]), fmaxf(s[i][2], s[i][3]));
#pragma unroll
      for (int msk = 1; msk < 16; msk <<= 1)
        rm = fmaxf(rm, __shfl_xor(rm, msk));
      const float mn = fmaxf(m[i], rm);
      const float sc = __expf(m[i] - mn);
      l[i] *= sc;
#pragma unroll
      for (int j = 0; j < 4; ++j) o[i][j] *= sc;
      float ps = 0.f;
#pragma unroll
      for (int j = 0; j < 4; ++j) { p[i][j] = __expf(s[i][j] - mn); ps += p[i][j]; }
#pragma unroll
      for (int msk = 1; msk < 16; msk <<= 1)
        ps += __shfl_xor(ps, msk);
      l[i] += ps;
      m[i] = mn;
    }

    __syncthreads();
#pragma unroll
    for (int i = 0; i < 4; ++i)
#pragma unroll
      for (int j = 0; j < 4; ++j)
        KPs[ty * 4 + i][tx * 4 + j] = p[i][j];
    __syncthreads();

#pragma unroll 8
    for (int sx = 0; sx < 64; ++sx) {
      float pa[4], vb[4];
#pragma unroll
      for (int i = 0; i < 4; ++i) pa[i] = KPs[ty * 4 + i][sx];
#pragma unroll
      for (int j = 0; j < 4; ++j) vb[j] = Vs[sx][tx * 4 + j];
#pragma unroll
      for (int i = 0; i < 4; ++i)
#pragma unroll
        for (int j = 0; j < 4; ++j)
          o[i][j] += pa[i] * vb[j];
    }
  }

#pragma unroll
  for (int i = 0; i < 4; ++i) {
    const float inv = 1.f / l[i];
    ushortx4 ov;
#pragma unroll
    for (int j = 0; j < 4; ++j) ov[j] = f2bf(o[i][j] * inv);
    *(ushortx4*)(O + (((size_t)b * SN + qt * 64 + ty * 4 + i) * HN + h) * DKN + tx * 4) = ov;
  }
}

extern "C" void kernel_launch(void* const* d_in, const int* in_sizes, int n_in,
                              void* d_out, int out_size, void* d_ws, size_t ws_size,
                              hipStream_t stream) {
  const float* x_enc = (const float*)d_in[0];
  const float* x_dec = (const float*)d_in[1];
  const float* mq_w = (const float*)d_in[2];  const float* mq_b = (const float*)d_in[3];
  const float* mk_w = (const float*)d_in[4];  const float* mk_b = (const float*)d_in[5];
  const float* mv_w = (const float*)d_in[6];  const float* mv_b = (const float*)d_in[7];
  const float* mo_w = (const float*)d_in[8];  const float* mo_b = (const float*)d_in[9];
  const float* cq_w = (const float*)d_in[10]; const float* cq_b = (const float*)d_in[11];
  const float* ck_w = (const float*)d_in[12]; const float* ck_b = (const float*)d_in[13];
  const float* cv_w = (const float*)d_in[14]; const float* cv_b = (const float*)d_in[15];
  const float* co_w = (const float*)d_in[16]; const float* co_b = (const float*)d_in[17];
  const float* f1_w = (const float*)d_in[18]; const float* f1_b = (const float*)d_in[19];
  const float* f2_w = (const float*)d_in[20]; const float* f2_b = (const float*)d_in[21];
  float* out = (float*)d_out;

  // ---- workspace layout (bytes) ----
  const size_t NTOK = (size_t)BN * SN;           // 8192
  char* wsb = (char*)d_ws;
  float* o5  = (float*)(wsb + 0);                 // current, fp32, 16 MB
  float* o6  = (float*)(wsb + (16u << 20));       // result,  fp32, 16 MB
  u16* Qb    = (u16*)(wsb + (32u << 20));         // 8 MB
  u16* Kb    = (u16*)(wsb + (40u << 20));         // 8 MB
  u16* Vb    = (u16*)(wsb + (48u << 20));         // 8 MB
  u16* B0    = (u16*)(wsb + (56u << 20));         // bf16 scratch (LN out / concat), 8 MB
  u16* B1    = (u16*)(wsb + (64u << 20));         // bf16 scratch (enc_n), 8 MB
  u16* FF1   = (u16*)(wsb + (72u << 20));         // [8192,2048] bf16, 32 MB
  u16* WB    = (u16*)(wsb + (104u << 20));        // bf16 weights, 8 MB
  float2* part = (float2*)(wsb + (112u << 20));   // LN partials

  u16* wb_mq = WB + 0 * 262144; u16* wb_mk = WB + 1 * 262144;
  u16* wb_mv = WB + 2 * 262144; u16* wb_mo = WB + 3 * 262144;
  u16* wb_cq = WB + 4 * 262144; u16* wb_ck = WB + 5 * 262144;
  u16* wb_cv = WB + 6 * 262144; u16* wb_co = WB + 7 * 262144;
  u16* wb_f1 = WB + 8 * 262144; u16* wb_f2 = WB + 8 * 262144 + 1048576;

  const int M = (int)NTOK;
  dim3 ln_grid(64, BN);
  dim3 g512(512 / 128, M / 128);
  dim3 g2048(2048 / 128, M / 128);
  dim3 attn_grid(SN / 64, HN, BN);

  cvt_weights<<<4096, 256, 0, stream>>>(mq_w, mk_w, mv_w, mo_w, cq_w, ck_w, cv_w, co_w,
                                        f1_w, f2_w, WB);

  // ---- masked self-attention block ----
  ln_sum<<<ln_grid, 256, 0, stream>>>(x_dec, part);
  ln_norm<<<ln_grid, 256, 0, stream>>>(x_dec, part, B0);
  gemm_mfma<false, false, true><<<g512, 256, 0, stream>>>(B0, wb_mq, mq_b, nullptr, Qb, M, 512, 512);
  gemm_mfma<false, false, true><<<g512, 256, 0, stream>>>(B0, wb_mk, mk_b, nullptr, Kb, M, 512, 512);
  gemm_mfma<false, false, true><<<g512, 256, 0, stream>>>(B0, wb_mv, mv_b, nullptr, Vb, M, 512, 512);
  attn_tile<1><<<attn_grid, 256, 0, stream>>>(Qb, Kb, Vb, B0);
  gemm_mfma<false, true, false><<<g512, 256, 0, stream>>>(B0, wb_mo, mo_b, x_dec, o5, M, 512, 512);

  // ---- cross-attention block ----
  ln_sum<<<ln_grid, 256, 0, stream>>>(o5, part);
  ln_norm<<<ln_grid, 256, 0, stream>>>(o5, part, B0);      // cur_n
  ln_sum<<<ln_grid, 256, 0, stream>>>(x_enc, part);
  ln_norm<<<ln_grid, 256, 0, stream>>>(x_enc, part, B1);   // enc_n
  gemm_mfma<false, false, true><<<g512, 256, 0, stream>>>(B0, wb_cq, cq_b, nullptr, Qb, M, 512, 512);
  gemm_mfma<false, false, true><<<g512, 256, 0, stream>>>(B1, wb_ck, ck_b, nullptr, Kb, M, 512, 512);
  gemm_mfma<false, false, true><<<g512, 256, 0, stream>>>(B1, wb_cv, cv_b, nullptr, Vb, M, 512, 512);
  attn_tile<0><<<attn_grid, 256, 0, stream>>>(Qb, Kb, Vb, B0);
  gemm_mfma<false, true, false><<<g512, 256, 0, stream>>>(B0, wb_co, co_b, o5, o6, M, 512, 512);

  // ---- feedforward block ----
  ln_sum<<<ln_grid, 256, 0, stream>>>(o6, part);
  ln_norm<<<ln_grid, 256, 0, stream>>>(o6, part, B0);      // res_n
  gemm_mfma<true, false, true><<<g2048, 256, 0, stream>>>(B0, wb_f1, f1_b, nullptr, FF1, M, 2048, 512);
  gemm_mfma<false, true, false><<<g512, 256, 0, stream>>>(FF1, wb_f2, f2_b, o6, out, M, 512, 2048);
}

// Round 4
// 375.493 us; speedup vs baseline: 26.8406x; 2.5999x over previous
//
#include <hip/hip_runtime.h>
#include <cmath>
#include <cstddef>
#include <cstdint>

// Problem constants
#define BN   8
#define SN   1024
#define DMN  512
#define HN   8
#define DKN  64
#define DFFN 2048

typedef short           bf16x8   __attribute__((ext_vector_type(8)));
typedef float           f32x4    __attribute__((ext_vector_type(4)));
typedef unsigned short  ushortx4 __attribute__((ext_vector_type(4)));
typedef unsigned short  ushortx8 __attribute__((ext_vector_type(8)));
typedef unsigned short  u16;

__device__ __forceinline__ float bf2f(u16 u) {
  return __uint_as_float(((unsigned int)u) << 16);
}
__device__ __forceinline__ u16 f2bf(float f) {
  unsigned int u = __float_as_uint(f);
  u += 0x7FFFu + ((u >> 16) & 1u);          // RNE
  return (u16)(u >> 16);
}
__device__ __forceinline__ void gload_lds16(const u16* gsrc, u16* ldst) {
  __builtin_amdgcn_global_load_lds(
      (const __attribute__((address_space(1))) unsigned int*)gsrc,
      (__attribute__((address_space(3))) unsigned int*)ldst,
      16, 0, 0);
}

// ---------------- weight fp32 -> bf16 conversion ----------------
__global__ __launch_bounds__(256) void cvt_weights(
    const float* p0, const float* p1, const float* p2, const float* p3,
    const float* p4, const float* p5, const float* p6, const float* p7,
    const float* p8, const float* p9, u16* __restrict__ dst) {
  const int gi = blockIdx.x * 256 + threadIdx.x;   // group of 4 elems
  const int idx = gi * 4;
  const float* src; int off;
  if (idx < 2097152) {
    const int t = idx >> 18; off = idx & 262143;
    switch (t) {
      case 0: src = p0; break; case 1: src = p1; break;
      case 2: src = p2; break; case 3: src = p3; break;
      case 4: src = p4; break; case 5: src = p5; break;
      case 6: src = p6; break; default: src = p7; break;
    }
  } else if (idx < 3145728) { src = p8; off = idx - 2097152; }
  else                      { src = p9; off = idx - 3145728; }
  float4 v = *(const float4*)(src + off);
  ushortx4 o;
  o[0] = f2bf(v.x); o[1] = f2bf(v.y); o[2] = f2bf(v.z); o[3] = f2bf(v.w);
  *(ushortx4*)(dst + idx) = o;
}

// ---------------- Global LayerNorm (two-pass), bf16 out ----------------
__global__ __launch_bounds__(256) void ln_sum(const float* __restrict__ X,
                                              float2* __restrict__ part) {
  const int g = blockIdx.x, b = blockIdx.y, t = threadIdx.x;
  const float4* Xv = (const float4*)(X + (size_t)b * (SN * DMN) + (size_t)g * 8192);
  float s = 0.f, s2 = 0.f;
#pragma unroll
  for (int it = 0; it < 8; ++it) {
    float4 x = Xv[t + it * 256];
    s  += x.x + x.y + x.z + x.w;
    s2 += x.x*x.x + x.y*x.y + x.z*x.z + x.w*x.w;
  }
  __shared__ float rs[256], rq[256];
  rs[t] = s; rq[t] = s2;
  __syncthreads();
  for (int off = 128; off > 0; off >>= 1) {
    if (t < off) { rs[t] += rs[t + off]; rq[t] += rq[t + off]; }
    __syncthreads();
  }
  if (t == 0) part[b * 64 + g] = make_float2(rs[0], rq[0]);
}

__global__ __launch_bounds__(256) void ln_norm(const float* __restrict__ X,
                                               const float2* __restrict__ part,
                                               u16* __restrict__ Y) {
  const int g = blockIdx.x, b = blockIdx.y, t = threadIdx.x;
  __shared__ float ss[64], sq[64];
  if (t < 64) { float2 p = part[b * 64 + t]; ss[t] = p.x; sq[t] = p.y; }
  __syncthreads();
  float s = 0.f, q = 0.f;
#pragma unroll
  for (int j = 0; j < 64; ++j) { s += ss[j]; q += sq[j]; }
  const float inv_n = 1.f / (float)(SN * DMN);
  const float mu = s * inv_n;
  const float var = q * inv_n - mu * mu;
  const float rstd = rsqrtf(var + 1e-5f);
  const size_t base = (size_t)b * (SN * DMN) + (size_t)g * 8192;
  const float4* Xv = (const float4*)(X + base);
#pragma unroll
  for (int it = 0; it < 8; ++it) {
    float4 x = Xv[t + it * 256];
    ushortx4 o;
    o[0] = f2bf((x.x - mu) * rstd); o[1] = f2bf((x.y - mu) * rstd);
    o[2] = f2bf((x.z - mu) * rstd); o[3] = f2bf((x.w - mu) * rstd);
    *(ushortx4*)(Y + base + (size_t)(t + it * 256) * 4) = o;
  }
}

// ---------------- bf16 MFMA GEMM ----------------
// OMODE: 0 = fp32 out, 1 = bf16 out, 2 = bf16 out transposed per-head (VT[b][h][d][s])
template<bool RELU, bool RES, int OMODE>
__global__ __launch_bounds__(256) void gemm_mfma(const u16* __restrict__ A,
                                                 const u16* __restrict__ W,
                                                 const float* __restrict__ bias,
                                                 const float* __restrict__ res,
                                                 void* __restrict__ Cv,
                                                 int M, int N, int K) {
  __shared__ u16 As[128 * 32];
  __shared__ u16 Bs[128 * 32];
  const int t = threadIdx.x;
  const int lane = t & 63, w = t >> 6;
  const int wm = w >> 1, wn = w & 1;
  const int m0 = blockIdx.y * 128, n0 = blockIdx.x * 128;

  f32x4 acc[4][4];
#pragma unroll
  for (int i = 0; i < 4; ++i)
#pragma unroll
    for (int j = 0; j < 4; ++j)
      acc[i][j] = (f32x4){0.f, 0.f, 0.f, 0.f};

  const int lrow = lane >> 2;
  const int lcol = (lane & 3) * 8;
  const int rofs = (lane & 15) * 32 + (lane >> 4) * 8;

  for (int k0 = 0; k0 < K; k0 += 32) {
#pragma unroll
    for (int c = 0; c < 2; ++c) {
      const int r0 = w * 32 + c * 16;
      gload_lds16(A + (size_t)(m0 + r0 + lrow) * K + k0 + lcol, &As[r0 * 32]);
      gload_lds16(W + (size_t)(n0 + r0 + lrow) * K + k0 + lcol, &Bs[r0 * 32]);
    }
    __syncthreads();
    bf16x8 af[4], bfr[4];
#pragma unroll
    for (int f = 0; f < 4; ++f) {
      af[f]  = *(const bf16x8*)&As[(wm * 64 + f * 16) * 32 + rofs];
      bfr[f] = *(const bf16x8*)&Bs[(wn * 64 + f * 16) * 32 + rofs];
    }
#pragma unroll
    for (int i = 0; i < 4; ++i)
#pragma unroll
      for (int j = 0; j < 4; ++j)
        acc[i][j] = __builtin_amdgcn_mfma_f32_16x16x32_bf16(af[i], bfr[j], acc[i][j], 0, 0, 0);
    __syncthreads();
  }

  const int crow0 = (lane >> 4) * 4;
  const int ccol  = lane & 15;
  float bv[4];
#pragma unroll
  for (int j = 0; j < 4; ++j) bv[j] = bias[n0 + wn * 64 + j * 16 + ccol];
#pragma unroll
  for (int i = 0; i < 4; ++i) {
#pragma unroll
    for (int r = 0; r < 4; ++r) {
      const int m = m0 + wm * 64 + i * 16 + crow0 + r;
#pragma unroll
      for (int j = 0; j < 4; ++j) {
        const int n = n0 + wn * 64 + j * 16 + ccol;
        float v = acc[i][j][r] + bv[j];
        if (RELU) v = fmaxf(v, 0.f);
        if (RES)  v += res[(size_t)m * N + n];
        if (OMODE == 0) {
          ((float*)Cv)[(size_t)m * N + n] = v;
        } else if (OMODE == 1) {
          ((u16*)Cv)[(size_t)m * N + n] = f2bf(v);
        } else {
          // VT[b][h][d][s]: b=m>>10, s=m&1023, h=n>>6, d=n&63
          ((u16*)Cv)[(((size_t)(m >> 10) * HN + (n >> 6)) * 64 + (n & 63)) * SN + (m & 1023)] = f2bf(v);
        }
      }
    }
  }
}

// ---------------- MFMA flash attention ----------------
// Q,K: [B,S,H*64] bf16;  VT: [B,H,64,S] bf16;  O: [B,S,H*64] bf16.
// Block: 4 waves, QBLK=128 (wave owns 32 q-rows), KVBLK=64.
#define QBLK 128
#define KVB  64
// XOR swizzle (G4): elem-index col ^ ((row&7)<<3)  == byte ^ ((row&7)<<4)
#define SWZ(row, col) ((row) * 64 + ((col) ^ (((row) & 7) << 3)))

template<int CAUSAL>
__global__ __launch_bounds__(256) void attn_mfma(const u16* __restrict__ Q,
                                                 const u16* __restrict__ K,
                                                 const u16* __restrict__ VT,
                                                 u16* __restrict__ O) {
  const int qb = blockIdx.x;
  const int bh = blockIdx.y;
  const int b = bh >> 3, h = bh & 7;
  const int t = threadIdx.x;
  const int lane = t & 63, w = t >> 6;
  const int l15 = lane & 15, l4 = lane >> 4;

  __shared__ __align__(16) u16 Qs[QBLK * 64];
  __shared__ __align__(16) u16 Ks[KVB * 64];
  __shared__ __align__(16) u16 Vts[64 * KVB];
  __shared__ __align__(16) u16 Ps[QBLK * 64];

  const int qbase = qb * QBLK;

  // stage Q tile (swizzled)
  {
    const int qr = t >> 1, qc = (t & 1) * 32;
    const u16* qg = Q + ((size_t)(b * SN + qbase + qr) * 512) + h * 64 + qc;
#pragma unroll
    for (int u = 0; u < 4; ++u) {
      ushortx8 v = *(const ushortx8*)(qg + u * 8);
      *(ushortx8*)&Qs[SWZ(qr, qc + u * 8)] = v;
    }
  }
  __syncthreads();

  // hoist Q fragments
  bf16x8 aq[2][2];
#pragma unroll
  for (int i = 0; i < 2; ++i)
#pragma unroll
    for (int ds = 0; ds < 2; ++ds) {
      const int row = w * 32 + i * 16 + l15;
      aq[i][ds] = *(const bf16x8*)&Qs[SWZ(row, ds * 32 + l4 * 8)];
    }

  f32x4 acc_o[2][4];
#pragma unroll
  for (int i = 0; i < 2; ++i)
#pragma unroll
    for (int jd = 0; jd < 4; ++jd)
      acc_o[i][jd] = (f32x4){0.f, 0.f, 0.f, 0.f};
  float mrow[2][4], lrow[2][4];
#pragma unroll
  for (int i = 0; i < 2; ++i)
#pragma unroll
    for (int r = 0; r < 4; ++r) { mrow[i][r] = -INFINITY; lrow[i][r] = 0.f; }

  const int nkt = CAUSAL ? (2 * qb + 2) : (SN / KVB);
  for (int kt = 0; kt < nkt; ++kt) {
    const int k0 = kt * KVB;
    __syncthreads();
    // stage K and VT tiles (reg-staged, swizzled)
    {
      const int r = t >> 2, c = (t & 3) * 16;
      const u16* kg = K + ((size_t)(b * SN + k0 + r) * 512) + h * 64 + c;
      ushortx8 ka = *(const ushortx8*)kg;
      ushortx8 kb = *(const ushortx8*)(kg + 8);
      const u16* vg = VT + ((size_t)bh * 64 + r) * SN + k0 + c;
      ushortx8 va = *(const ushortx8*)vg;
      ushortx8 vb = *(const ushortx8*)(vg + 8);
      *(ushortx8*)&Ks[SWZ(r, c)]      = ka;
      *(ushortx8*)&Ks[SWZ(r, c + 8)]  = kb;
      *(ushortx8*)&Vts[SWZ(r, c)]     = va;
      *(ushortx8*)&Vts[SWZ(r, c + 8)] = vb;
    }
    __syncthreads();

    // waves with no unmasked work skip compute (no barriers inside)
    if (CAUSAL && k0 > qbase + w * 32 + 31) continue;

    // QK^T: s[i][j] (q-tile i of 2, k-tile j of 4)
    f32x4 s[2][4];
#pragma unroll
    for (int i = 0; i < 2; ++i)
#pragma unroll
      for (int j = 0; j < 4; ++j)
        s[i][j] = (f32x4){0.f, 0.f, 0.f, 0.f};
#pragma unroll
    for (int ds = 0; ds < 2; ++ds) {
      bf16x8 bk[4];
#pragma unroll
      for (int j = 0; j < 4; ++j) {
        const int row = j * 16 + l15;
        bk[j] = *(const bf16x8*)&Ks[SWZ(row, ds * 32 + l4 * 8)];
      }
#pragma unroll
      for (int i = 0; i < 2; ++i)
#pragma unroll
        for (int j = 0; j < 4; ++j)
          s[i][j] = __builtin_amdgcn_mfma_f32_16x16x32_bf16(aq[i][ds], bk[j], s[i][j], 0, 0, 0);
    }

    const bool domask = CAUSAL && (k0 + KVB - 1 > qbase + w * 32);
#pragma unroll
    for (int i = 0; i < 2; ++i) {
      const int qr0 = qbase + w * 32 + i * 16 + l4 * 4;
#pragma unroll
      for (int r = 0; r < 4; ++r) {
        float sv[4];
#pragma unroll
        for (int j = 0; j < 4; ++j) {
          sv[j] = s[i][j][r] * 0.125f;
          if (domask && (k0 + j * 16 + l15 > qr0 + r)) sv[j] = -INFINITY;
        }
        float rm = fmaxf(fmaxf(sv[0], sv[1]), fmaxf(sv[2], sv[3]));
#pragma unroll
        for (int msk = 1; msk < 16; msk <<= 1)
          rm = fmaxf(rm, __shfl_xor(rm, msk));
        const float mn = fmaxf(mrow[i][r], rm);
        const float al = __expf(mrow[i][r] - mn);
        mrow[i][r] = mn;
        float ps = 0.f;
        u16 pb[4];
#pragma unroll
        for (int j = 0; j < 4; ++j) {
          float p = __expf(sv[j] - mn);
          ps += p;
          pb[j] = f2bf(p);
        }
#pragma unroll
        for (int msk = 1; msk < 16; msk <<= 1)
          ps += __shfl_xor(ps, msk);
        lrow[i][r] = lrow[i][r] * al + ps;
#pragma unroll
        for (int jd = 0; jd < 4; ++jd) acc_o[i][jd][r] *= al;
        const int prow = w * 32 + i * 16 + l4 * 4 + r;
#pragma unroll
        for (int j = 0; j < 4; ++j)
          Ps[SWZ(prow, j * 16 + l15)] = pb[j];
      }
    }

    // PV: O += P . V  (P wave-local in LDS; Vts shared, read-only since barrier)
#pragma unroll
    for (int ks = 0; ks < 2; ++ks) {
      bf16x8 ap[2], bv[4];
#pragma unroll
      for (int i = 0; i < 2; ++i) {
        const int row = w * 32 + i * 16 + l15;
        ap[i] = *(const bf16x8*)&Ps[SWZ(row, ks * 32 + l4 * 8)];
      }
#pragma unroll
      for (int jd = 0; jd < 4; ++jd) {
        const int row = jd * 16 + l15;
        bv[jd] = *(const bf16x8*)&Vts[SWZ(row, ks * 32 + l4 * 8)];
      }
#pragma unroll
      for (int i = 0; i < 2; ++i)
#pragma unroll
        for (int jd = 0; jd < 4; ++jd)
          acc_o[i][jd] = __builtin_amdgcn_mfma_f32_16x16x32_bf16(ap[i], bv[jd], acc_o[i][jd], 0, 0, 0);
    }
  }

  // epilogue: O = acc_o / l
#pragma unroll
  for (int i = 0; i < 2; ++i) {
#pragma unroll
    for (int r = 0; r < 4; ++r) {
      const float inv = 1.f / lrow[i][r];
      const int q = qbase + w * 32 + i * 16 + l4 * 4 + r;
      u16* op = O + ((size_t)(b * SN + q) * 512) + h * 64;
#pragma unroll
      for (int jd = 0; jd < 4; ++jd)
        op[jd * 16 + l15] = f2bf(acc_o[i][jd][r] * inv);
    }
  }
}

extern "C" void kernel_launch(void* const* d_in, const int* in_sizes, int n_in,
                              void* d_out, int out_size, void* d_ws, size_t ws_size,
                              hipStream_t stream) {
  const float* x_enc = (const float*)d_in[0];
  const float* x_dec = (const float*)d_in[1];
  const float* mq_w = (const float*)d_in[2];  const float* mq_b = (const float*)d_in[3];
  const float* mk_w = (const float*)d_in[4];  const float* mk_b = (const float*)d_in[5];
  const float* mv_w = (const float*)d_in[6];  const float* mv_b = (const float*)d_in[7];
  const float* mo_w = (const float*)d_in[8];  const float* mo_b = (const float*)d_in[9];
  const float* cq_w = (const float*)d_in[10]; const float* cq_b = (const float*)d_in[11];
  const float* ck_w = (const float*)d_in[12]; const float* ck_b = (const float*)d_in[13];
  const float* cv_w = (const float*)d_in[14]; const float* cv_b = (const float*)d_in[15];
  const float* co_w = (const float*)d_in[16]; const float* co_b = (const float*)d_in[17];
  const float* f1_w = (const float*)d_in[18]; const float* f1_b = (const float*)d_in[19];
  const float* f2_w = (const float*)d_in[20]; const float* f2_b = (const float*)d_in[21];
  float* out = (float*)d_out;

  // ---- workspace layout (bytes) ----
  char* wsb = (char*)d_ws;
  float* o5  = (float*)(wsb + 0);                 // current, fp32, 16 MB
  float* o6  = (float*)(wsb + (16u << 20));       // result,  fp32, 16 MB
  u16* Qb    = (u16*)(wsb + (32u << 20));         // 8 MB
  u16* Kb    = (u16*)(wsb + (40u << 20));         // 8 MB
  u16* VTb   = (u16*)(wsb + (48u << 20));         // 8 MB, [B,H,64,S]
  u16* B0    = (u16*)(wsb + (56u << 20));         // bf16 scratch, 8 MB
  u16* B1    = (u16*)(wsb + (64u << 20));         // bf16 scratch (enc_n), 8 MB
  u16* FF1   = (u16*)(wsb + (72u << 20));         // [8192,2048] bf16, 32 MB
  u16* WB    = (u16*)(wsb + (104u << 20));        // bf16 weights, 8 MB
  float2* part = (float2*)(wsb + (112u << 20));   // LN partials

  u16* wb_mq = WB + 0 * 262144; u16* wb_mk = WB + 1 * 262144;
  u16* wb_mv = WB + 2 * 262144; u16* wb_mo = WB + 3 * 262144;
  u16* wb_cq = WB + 4 * 262144; u16* wb_ck = WB + 5 * 262144;
  u16* wb_cv = WB + 6 * 262144; u16* wb_co = WB + 7 * 262144;
  u16* wb_f1 = WB + 8 * 262144; u16* wb_f2 = WB + 8 * 262144 + 1048576;

  const int M = BN * SN;  // 8192
  dim3 ln_grid(64, BN);
  dim3 g512(512 / 128, M / 128);
  dim3 g2048(2048 / 128, M / 128);
  dim3 attn_grid(SN / QBLK, BN * HN);

  cvt_weights<<<4096, 256, 0, stream>>>(mq_w, mk_w, mv_w, mo_w, cq_w, ck_w, cv_w, co_w,
                                        f1_w, f2_w, WB);

  // ---- masked self-attention block ----
  ln_sum<<<ln_grid, 256, 0, stream>>>(x_dec, part);
  ln_norm<<<ln_grid, 256, 0, stream>>>(x_dec, part, B0);
  gemm_mfma<false, false, 1><<<g512, 256, 0, stream>>>(B0, wb_mq, mq_b, nullptr, Qb, M, 512, 512);
  gemm_mfma<false, false, 1><<<g512, 256, 0, stream>>>(B0, wb_mk, mk_b, nullptr, Kb, M, 512, 512);
  gemm_mfma<false, false, 2><<<g512, 256, 0, stream>>>(B0, wb_mv, mv_b, nullptr, VTb, M, 512, 512);
  attn_mfma<1><<<attn_grid, 256, 0, stream>>>(Qb, Kb, VTb, B0);
  gemm_mfma<false, true, 0><<<g512, 256, 0, stream>>>(B0, wb_mo, mo_b, x_dec, o5, M, 512, 512);

  // ---- cross-attention block ----
  ln_sum<<<ln_grid, 256, 0, stream>>>(o5, part);
  ln_norm<<<ln_grid, 256, 0, stream>>>(o5, part, B0);      // cur_n
  ln_sum<<<ln_grid, 256, 0, stream>>>(x_enc, part);
  ln_norm<<<ln_grid, 256, 0, stream>>>(x_enc, part, B1);   // enc_n
  gemm_mfma<false, false, 1><<<g512, 256, 0, stream>>>(B0, wb_cq, cq_b, nullptr, Qb, M, 512, 512);
  gemm_mfma<false, false, 1><<<g512, 256, 0, stream>>>(B1, wb_ck, ck_b, nullptr, Kb, M, 512, 512);
  gemm_mfma<false, false, 2><<<g512, 256, 0, stream>>>(B1, wb_cv, cv_b, nullptr, VTb, M, 512, 512);
  attn_mfma<0><<<attn_grid, 256, 0, stream>>>(Qb, Kb, VTb, B0);
  gemm_mfma<false, true, 0><<<g512, 256, 0, stream>>>(B0, wb_co, co_b, o5, o6, M, 512, 512);

  // ---- feedforward block ----
  ln_sum<<<ln_grid, 256, 0, stream>>>(o6, part);
  ln_norm<<<ln_grid, 256, 0, stream>>>(o6, part, B0);      // res_n
  gemm_mfma<true, false, 1><<<g2048, 256, 0, stream>>>(B0, wb_f1, f1_b, nullptr, FF1, M, 2048, 512);
  gemm_mfma<false, true, 0><<<g512, 256, 0, stream>>>(FF1, wb_f2, f2_b, o6, out, M, 512, 2048);
}